// Round 8
// baseline (623.464 us; speedup 1.0000x reference)
//
#include <hip/hip_runtime.h>
#include <hip/hip_cooperative_groups.h>

namespace cg = cooperative_groups;

namespace {

typedef unsigned short ushort_t;
typedef unsigned int uint_t;
typedef __attribute__((ext_vector_type(8))) short bf16x8;
typedef __attribute__((ext_vector_type(4))) float f32x4;

constexpr int N   = 50000;
constexpr int E   = 600000;
constexpr int NR  = 5;
constexpr int KIN = 768;
constexpr int H   = 128;
constexpr int RD  = 200;

__device__ inline ushort_t f2b(float f){           // fp32 -> bf16 bits, RNE
  uint_t u = __builtin_bit_cast(uint_t, f);
  uint_t r = (u + 0x7FFFu + ((u >> 16) & 1u)) >> 16;
  return (ushort_t)r;
}
__device__ inline float b2f_lo(uint_t u){ return __builtin_bit_cast(float, u << 16); }
__device__ inline float b2f_hi(uint_t u){ return __builtin_bit_cast(float, u & 0xFFFF0000u); }
__device__ inline float b2f_us(ushort_t h){ return __builtin_bit_cast(float, ((uint_t)h) << 16); }
__device__ inline uint_t cvtpk(float lo, float hi){ // 2x fp32 -> packed bf16 (RNE), 1 instr
  uint_t r;
  asm("v_cvt_pk_bf16_f32 %0, %1, %2" : "=v"(r) : "v"(lo), "v"(hi));
  return r;
}

// ===== cooperative prep + CSR build: one dispatch, 4 grid.sync()s =====
// P0: zero deg + weight cvt (grid-stride) + relsc (blocks 0,1)
// P1: degcount (atomics)   P2: per-chunk scan   P3: prefix-add   P4: fill
__global__ void csr_k(
    const float* __restrict__ l1W, const float* __restrict__ W1,
    const float* __restrict__ R1, const float* __restrict__ W2,
    const float* __restrict__ R2, const float* __restrict__ l2W,
    ushort_t* __restrict__ wts,
    const float* __restrict__ rel1, const float* __restrict__ Wr1,
    const float* __restrict__ a1, float* __restrict__ sC1,
    const float* __restrict__ rel2, const float* __restrict__ Wr2,
    const float* __restrict__ a2, float* __restrict__ sC2,
    const int* __restrict__ esrc, const int* __restrict__ edst,
    const int* __restrict__ et,
    int* __restrict__ deg, int* __restrict__ rowptr, int* __restrict__ cursor,
    int* __restrict__ bsums, int* __restrict__ cpk)
{
  cg::grid_group grid = cg::this_grid();
  constexpr int S0 = H * KIN;        // 98304
  constexpr int S1 = H * H;          // 16384
  constexpr int TOT = S0 + 5 * S1;   // 180224
  constexpr int NB = (N + 255) / 256;  // 196
  __shared__ int   s[256];
  __shared__ float red[256];
  const int tid = threadIdx.x;
  const int gid = blockIdx.x * 256 + tid;
  const int gsz = gridDim.x * 256;

  // ---- P0 ----
  for (int i = gid; i < N; i += gsz) deg[i] = 0;
  for (int i = gid; i < TOT; i += gsz){
    float v;
    if (i < S0) v = l1W[i];
    else {
      int j = i - S0, seg = j >> 14, off = j & (S1 - 1);
      const float* srcs[5] = {W1, R1, W2, R2, l2W};
      v = srcs[seg][off];
    }
    wts[i] = f2b(v);
  }
  if (blockIdx.x < 2){               // relation scalars, one block per layer
    int L = blockIdx.x;
    const float* rel = L ? rel2 : rel1;
    const float* Wr  = L ? Wr2  : Wr1;
    const float* a   = L ? a2   : a1;
    float*       sC  = L ? sC2  : sC1;
    int n = tid >> 1, half = tid & 1;
    float aC = a[256 + n];
    for (int r = 0; r < NR; ++r){
      float p = 0.f;
      for (int k = half * 100; k < half * 100 + 100; ++k)
        p += rel[r * RD + k] * Wr[n * RD + k];
      red[tid] = p * aC;
      __syncthreads();
      for (int ss = 128; ss > 0; ss >>= 1){
        if (tid < ss) red[tid] += red[tid + ss];
        __syncthreads();
      }
      if (tid == 0) sC[r] = red[0];
      __syncthreads();
    }
  }
  grid.sync();

  // ---- P1: degree count ----
  for (int e = gid; e < E; e += gsz) atomicAdd(&deg[edst[e]], 1);
  grid.sync();

  // ---- P2: per-chunk exclusive scan ----
  if (blockIdx.x < NB){
    int i = blockIdx.x * 256 + tid;
    int v = (i < N) ? deg[i] : 0;
    s[tid] = v; __syncthreads();
    for (int off = 1; off < 256; off <<= 1){
      int t = (tid >= off) ? s[tid - off] : 0;
      __syncthreads();
      s[tid] += t;
      __syncthreads();
    }
    if (i < N) rowptr[i] = s[tid] - v;
    if (tid == 255) bsums[blockIdx.x] = s[255];
  }
  grid.sync();

  // ---- P3: block-prefix add (every active block scans bsums redundantly) ----
  if (blockIdx.x < NB){
    int v = (tid < NB) ? bsums[tid] : 0;
    s[tid] = v; __syncthreads();
    for (int off = 1; off < 256; off <<= 1){
      int t = (tid >= off) ? s[tid - off] : 0;
      __syncthreads();
      s[tid] += t;
      __syncthreads();
    }
    int add = s[blockIdx.x] - bsums[blockIdx.x];   // exclusive prefix of this block
    int i = blockIdx.x * 256 + tid;
    if (i < N){
      int val = rowptr[i] + add;
      rowptr[i] = val; cursor[i] = val;
    }
    if (i == 0) rowptr[N] = E;
  }
  grid.sync();

  // ---- P4: fill packed adjacency (type<<16)|src ----
  for (int e = gid; e < E; e += gsz){
    int d = edst[e];
    int p = atomicAdd(&cursor[d], 1);
    cpk[p] = esrc[e] | (et[e] << 16);
  }
}

// --------- fused [agg +] double-GEMM, shared impl; BK=64 k-step ---------
// 64x128 tile, 4 waves, 2-phase reg prefetch; GEMM2 B staged in dead U region.
// M1: 1 = +bias1, leaky(0.01)    2 = in-block agg (16-lane grp/node) + elu(acc+agg)
// NORM: row L2-normalize; STORE1: bf16 stage-1 out; M2: 1 = fp32 out, 3 = bf16 + sA/sB
template<int K1, int M1, bool AFP32, bool NORM, bool STORE1, int M2>
__device__ __forceinline__ void gfused_impl(
    const void* __restrict__ Ap, const ushort_t* __restrict__ Wb1,
    const float* __restrict__ bias1,
    const ushort_t* __restrict__ WxG, const int* __restrict__ rowptr,
    const int* __restrict__ cpk, const float* __restrict__ sAi,
    const float* __restrict__ sBi, const float* __restrict__ sCi,
    ushort_t* __restrict__ out1,
    const ushort_t* __restrict__ Wb2, const float* __restrict__ vec2,
    void* __restrict__ out2, float* __restrict__ sAo, float* __restrict__ sBo, int M)
{
  constexpr int BK = 64;               // k-step
  constexpr int NT = K1 / BK;          // 12 (G1) or 2 (G2/G3)
  constexpr int SP = 72;               // staging row stride (bf16 elems), 144 B
  constexpr int CP = 136;              // Cs/B2s stride; 272 B rows
  __shared__ __align__(16) ushort_t U[128 * CP];   // 34816 B: As+Bs | B2s overlay
  __shared__ __align__(16) ushort_t Cs[64 * CP];   // 17408 B
  ushort_t* const As  = U;                          // 64 x SP   (9216 B)
  ushort_t* const Bs  = U + 64 * SP;                // 128 x SP  (18432 B; tot 27648)
  ushort_t* const B2s = U;                          // 128 x CP after GEMM1
  const int tid  = threadIdx.x;
  const int wave = tid >> 6, lane = tid & 63;
  const int l15  = lane & 15, quad = lane >> 4;
  const int row0 = blockIdx.x * 64;

  // ---- M1==2: in-block aggregation for this block's 64 nodes -> Cs ----
  if (M1 == 2){
    const int grp = tid >> 4;       // 16 groups of 16 lanes
    const int l   = tid & 15;
    const int gb  = tid & 48;       // group base lane within wave
    #pragma unroll 1
    for (int nb = 0; nb < 4; ++nb){
      int lrow = nb * 16 + grp;
      int node = row0 + lrow;
      uint4 o = make_uint4(0, 0, 0, 0);
      if (node < M){
        int p0 = rowptr[node], p1 = rowptr[node + 1];
        int dg = p1 - p0;
        float sa = sAi[node];
        float m = -1e30f, ssum = 0.f;
        float a[8];
        #pragma unroll
        for (int j = 0; j < 8; ++j) a[j] = 0.f;
        for (int c0 = 0; c0 < dg; c0 += 16){
          int cnt = dg - c0; if (cnt > 16) cnt = 16;
          bool ok = l < cnt;
          int pk = cpk[p0 + c0 + (ok ? l : 0)];
          float s = sa + sBi[pk & 0xFFFF] + sCi[pk >> 16];
          s = s > 0.f ? s : 0.2f * s;                    // leaky_relu(., 0.2)
          float sv = ok ? s : -1e30f;
          #pragma unroll
          for (int off = 8; off > 0; off >>= 1) sv = fmaxf(sv, __shfl_xor(sv, off, 16));
          float mn = fmaxf(m, sv);
          float corr = __expf(m - mn);
          ssum *= corr;
          #pragma unroll
          for (int j = 0; j < 8; ++j) a[j] *= corr;
          float ev = ok ? __expf(s - mn) : 0.f;
          float es = ev;
          #pragma unroll
          for (int off = 8; off > 0; off >>= 1) es += __shfl_xor(es, off, 16);
          ssum += es;
          m = mn;
          int png = ok ? pk : 0;
          for (int e = 0; e < cnt; e += 4){              // tails neutralized by ev=0
            int b0l = gb + e;
            int pe0 = __shfl(png, b0l,     64), pe1 = __shfl(png, b0l + 1, 64);
            int pe2 = __shfl(png, b0l + 2, 64), pe3 = __shfl(png, b0l + 3, 64);
            float e0 = __shfl(ev, b0l,     64), e1 = __shfl(ev, b0l + 1, 64);
            float e2 = __shfl(ev, b0l + 2, 64), e3 = __shfl(ev, b0l + 3, 64);
            uint4 u0 = *reinterpret_cast<const uint4*>(WxG + (size_t)(pe0 & 0xFFFF) * 128 + l * 8);
            uint4 u1 = *reinterpret_cast<const uint4*>(WxG + (size_t)(pe1 & 0xFFFF) * 128 + l * 8);
            uint4 u2 = *reinterpret_cast<const uint4*>(WxG + (size_t)(pe2 & 0xFFFF) * 128 + l * 8);
            uint4 u3 = *reinterpret_cast<const uint4*>(WxG + (size_t)(pe3 & 0xFFFF) * 128 + l * 8);
            a[0] += e0 * b2f_lo(u0.x); a[1] += e0 * b2f_hi(u0.x);
            a[2] += e0 * b2f_lo(u0.y); a[3] += e0 * b2f_hi(u0.y);
            a[4] += e0 * b2f_lo(u0.z); a[5] += e0 * b2f_hi(u0.z);
            a[6] += e0 * b2f_lo(u0.w); a[7] += e0 * b2f_hi(u0.w);
            a[0] += e1 * b2f_lo(u1.x); a[1] += e1 * b2f_hi(u1.x);
            a[2] += e1 * b2f_lo(u1.y); a[3] += e1 * b2f_hi(u1.y);
            a[4] += e1 * b2f_lo(u1.z); a[5] += e1 * b2f_hi(u1.z);
            a[6] += e1 * b2f_lo(u1.w); a[7] += e1 * b2f_hi(u1.w);
            a[0] += e2 * b2f_lo(u2.x); a[1] += e2 * b2f_hi(u2.x);
            a[2] += e2 * b2f_lo(u2.y); a[3] += e2 * b2f_hi(u2.y);
            a[4] += e2 * b2f_lo(u2.z); a[5] += e2 * b2f_hi(u2.z);
            a[6] += e2 * b2f_lo(u2.w); a[7] += e2 * b2f_hi(u2.w);
            a[0] += e3 * b2f_lo(u3.x); a[1] += e3 * b2f_hi(u3.x);
            a[2] += e3 * b2f_lo(u3.y); a[3] += e3 * b2f_hi(u3.y);
            a[4] += e3 * b2f_lo(u3.z); a[5] += e3 * b2f_hi(u3.z);
            a[6] += e3 * b2f_lo(u3.w); a[7] += e3 * b2f_hi(u3.w);
          }
        }
        float inv = (dg > 0) ? 1.f / ssum : 0.f;        // degree-0 -> zero row
        o.x = cvtpk(a[0] * inv, a[1] * inv);
        o.y = cvtpk(a[2] * inv, a[3] * inv);
        o.z = cvtpk(a[4] * inv, a[5] * inv);
        o.w = cvtpk(a[6] * inv, a[7] * inv);
      }
      *reinterpret_cast<uint4*>(&Cs[lrow * CP + l * 8]) = o;   // cols l*8..l*8+7
    }
  }

  f32x4 acc[8];
  #pragma unroll
  for (int t = 0; t < 8; ++t) acc[t] = (f32x4){0.f, 0.f, 0.f, 0.f};

  // ================= GEMM 1: A[M x K1] @ W1^T, BK=64, prefetched =================
  const int ar = tid >> 2, aq = tid & 3;     // A: row 0..63, 16-elem seg
  const int agrow = row0 + ar;
  const bool aok = agrow < M;
  const int awoff = ar * SP + aq * 16;
  const int bn = tid >> 1, bs = (tid & 1) * 32;   // B: n-row, 32-elem half
  const ushort_t* bsrc = Wb1 + (size_t)bn * K1 + bs;

  float4 pf0, pf1, pf2, pf3;
  uint4  pu0, pu1;
  uint4  pb0, pb1, pb2, pb3;
  pf0 = pf1 = pf2 = pf3 = make_float4(0.f, 0.f, 0.f, 0.f);
  pu0 = pu1 = make_uint4(0, 0, 0, 0);

#define ISSUE_A(kk) do{ if (aok){                                               \
    if constexpr (AFP32){                                                       \
      const float* ap_ = (const float*)Ap + (size_t)agrow * K1 + (kk) + aq * 16; \
      pf0 = *reinterpret_cast<const float4*>(ap_);                              \
      pf1 = *reinterpret_cast<const float4*>(ap_ + 4);                          \
      pf2 = *reinterpret_cast<const float4*>(ap_ + 8);                          \
      pf3 = *reinterpret_cast<const float4*>(ap_ + 12);                         \
    } else {                                                                    \
      const ushort_t* apb_ = (const ushort_t*)Ap + (size_t)agrow * K1 + (kk) + aq * 16; \
      pu0 = *reinterpret_cast<const uint4*>(apb_);                              \
      pu1 = *reinterpret_cast<const uint4*>(apb_ + 8);                          \
    } } }while(0)

#define ISSUE_B(kk) do{                                                         \
    pb0 = *reinterpret_cast<const uint4*>(bsrc + (kk));                         \
    pb1 = *reinterpret_cast<const uint4*>(bsrc + (kk) + 8);                     \
    pb2 = *reinterpret_cast<const uint4*>(bsrc + (kk) + 16);                    \
    pb3 = *reinterpret_cast<const uint4*>(bsrc + (kk) + 24);                    \
  }while(0)

#define WRITE_AB() do{                                                          \
    uint4 av0_, av1_;                                                           \
    if constexpr (AFP32){                                                       \
      av0_.x = cvtpk(pf0.x, pf0.y); av0_.y = cvtpk(pf0.z, pf0.w);               \
      av0_.z = cvtpk(pf1.x, pf1.y); av0_.w = cvtpk(pf1.z, pf1.w);               \
      av1_.x = cvtpk(pf2.x, pf2.y); av1_.y = cvtpk(pf2.z, pf2.w);               \
      av1_.z = cvtpk(pf3.x, pf3.y); av1_.w = cvtpk(pf3.z, pf3.w);               \
    } else { av0_ = pu0; av1_ = pu1; }                                          \
    *reinterpret_cast<uint4*>(&As[awoff])     = av0_;                           \
    *reinterpret_cast<uint4*>(&As[awoff + 8]) = av1_;                           \
    *reinterpret_cast<uint4*>(&Bs[bn * SP + bs])      = pb0;                    \
    *reinterpret_cast<uint4*>(&Bs[bn * SP + bs + 8])  = pb1;                    \
    *reinterpret_cast<uint4*>(&Bs[bn * SP + bs + 16]) = pb2;                    \
    *reinterpret_cast<uint4*>(&Bs[bn * SP + bs + 24]) = pb3;                    \
  }while(0)

  ISSUE_A(0); ISSUE_B(0);
  for (int t = 0; t < NT; ++t){
    WRITE_AB();
    __syncthreads();
    if (t + 1 < NT){ ISSUE_A((t + 1) * BK); ISSUE_B((t + 1) * BK); }
    bf16x8 af0 = *reinterpret_cast<const bf16x8*>(&As[(wave * 16 + l15) * SP + quad * 8]);
    bf16x8 af1 = *reinterpret_cast<const bf16x8*>(&As[(wave * 16 + l15) * SP + 32 + quad * 8]);
    #pragma unroll
    for (int tt = 0; tt < 8; ++tt){
      bf16x8 b0 = *reinterpret_cast<const bf16x8*>(&Bs[(tt * 16 + l15) * SP + quad * 8]);
      acc[tt] = __builtin_amdgcn_mfma_f32_16x16x32_bf16(af0, b0, acc[tt], 0, 0, 0);
      bf16x8 b1 = *reinterpret_cast<const bf16x8*>(&Bs[(tt * 16 + l15) * SP + 32 + quad * 8]);
      acc[tt] = __builtin_amdgcn_mfma_f32_16x16x32_bf16(af1, b1, acc[tt], 0, 0, 0);
    }
    __syncthreads();
  }
#undef ISSUE_A
#undef ISSUE_B
#undef WRITE_AB

  // ---- issue GEMM2 B loads first (latency hides under epilogue-1 VALU) ----
  uint4 wreg[8];
  #pragma unroll
  for (int i = 0; i < 8; ++i){
    int idx = tid + 256 * i;                 // 2048 chunks of 8 bf16
    int rr = idx >> 4, c8 = idx & 15;
    wreg[i] = *reinterpret_cast<const uint4*>(Wb2 + (size_t)rr * 128 + c8 * 8);
  }

  // ---- epilogue 1: C/D map col=t*16+l15, local row lr=wave*16+quad*4+r ----
  float vv[8][4];
  #pragma unroll
  for (int t = 0; t < 8; ++t){
    #pragma unroll
    for (int r = 0; r < 4; ++r){
      int lr  = wave * 16 + quad * 4 + r;
      int col = t * 16 + l15;
      float v = acc[t][r];
      if (M1 == 1){
        v += bias1[col];
        v = v > 0.f ? v : 0.01f * v;
      } else { // M1 == 2
        v += b2f_us(Cs[lr * CP + col]);      // same cell this thread rewrites below
        v = v > 0.f ? v : __expf(v) - 1.f;
      }
      vv[t][r] = v;
    }
  }
  // write staged B2 (As/Bs region dead after last k-loop barrier)
  #pragma unroll
  for (int i = 0; i < 8; ++i){
    int idx = tid + 256 * i;
    int rr = idx >> 4, c8 = idx & 15;
    *reinterpret_cast<uint4*>(&B2s[rr * CP + c8 * 8]) = wreg[i];
  }
  if (NORM){
    #pragma unroll
    for (int r = 0; r < 4; ++r){
      float ss = 0.f;
      #pragma unroll
      for (int t = 0; t < 8; ++t) ss += vv[t][r] * vv[t][r];
      #pragma unroll
      for (int off = 1; off < 16; off <<= 1) ss += __shfl_xor(ss, off, 64);
      float sc = 1.f / fmaxf(sqrtf(ss), 1e-12f);
      #pragma unroll
      for (int t = 0; t < 8; ++t) vv[t][r] *= sc;
    }
  }
  #pragma unroll
  for (int t = 0; t < 8; t += 2){
    #pragma unroll
    for (int r = 0; r < 4; ++r){
      int lr  = wave * 16 + quad * 4 + r;
      int c0  = t * 16 + l15, c1 = c0 + 16;
      uint_t pr = cvtpk(vv[t][r], vv[t + 1][r]);
      Cs[lr * CP + c0] = (ushort_t)pr;
      Cs[lr * CP + c1] = (ushort_t)(pr >> 16);
      if (STORE1){
        int grow = row0 + lr;
        if (grow < M){
          out1[(size_t)grow * 128 + c0] = (ushort_t)pr;
          out1[(size_t)grow * 128 + c1] = (ushort_t)(pr >> 16);
        }
      }
    }
  }
  __syncthreads();

  // ================= GEMM 2: Cs[64 x 128] @ W2^T, fully staged =================
  #pragma unroll
  for (int t = 0; t < 8; ++t) acc[t] = (f32x4){0.f, 0.f, 0.f, 0.f};
  #pragma unroll
  for (int kk = 0; kk < 4; ++kk){
    bf16x8 af2 = *reinterpret_cast<const bf16x8*>(&Cs[(wave * 16 + l15) * CP + kk * 32 + quad * 8]);
    #pragma unroll
    for (int t = 0; t < 8; ++t){
      bf16x8 bfr = *reinterpret_cast<const bf16x8*>(&B2s[(t * 16 + l15) * CP + kk * 32 + quad * 8]);
      acc[t] = __builtin_amdgcn_mfma_f32_16x16x32_bf16(af2, bfr, acc[t], 0, 0, 0);
    }
  }

  // ---- epilogue 2 ----
  if (M2 == 1){
    #pragma unroll
    for (int t = 0; t < 8; ++t){
      #pragma unroll
      for (int r = 0; r < 4; ++r){
        int grow = row0 + wave * 16 + quad * 4 + r;
        if (grow >= M) continue;
        int col = t * 16 + l15;
        float v = acc[t][r] + vec2[col];
        v = v > 0.f ? v : 0.01f * v;
        ((float*)out2)[(size_t)grow * 128 + col] = v;
      }
    }
  } else { // M2 == 3: bf16 out + per-row sA/sB
    #pragma unroll
    for (int t = 0; t < 8; t += 2){
      #pragma unroll
      for (int r = 0; r < 4; ++r){
        int grow = row0 + wave * 16 + quad * 4 + r;
        if (grow >= M) continue;
        int c0 = t * 16 + l15;
        uint_t pr = cvtpk(acc[t][r], acc[t + 1][r]);
        ((ushort_t*)out2)[(size_t)grow * 128 + c0]      = (ushort_t)pr;
        ((ushort_t*)out2)[(size_t)grow * 128 + c0 + 16] = (ushort_t)(pr >> 16);
      }
    }
    #pragma unroll
    for (int r = 0; r < 4; ++r){
      float pa = 0.f, pb = 0.f;
      #pragma unroll
      for (int t = 0; t < 8; ++t){
        int col = t * 16 + l15;
        pa += acc[t][r] * vec2[col];
        pb += acc[t][r] * vec2[128 + col];
      }
      #pragma unroll
      for (int off = 1; off < 16; off <<= 1){
        pa += __shfl_xor(pa, off, 64);
        pb += __shfl_xor(pb, off, 64);
      }
      int grow = row0 + wave * 16 + quad * 4 + r;
      if (l15 == r && grow < M){ sAo[grow] = pa; sBo[grow] = pb; }
    }
  }
}

// ---- distinctly-named kernels per stage (rocprof visibility) ----
__global__ __launch_bounds__(256) void g1_k(
    const void* Ap, const ushort_t* Wb1, const float* bias1,
    ushort_t* out1, const ushort_t* Wb2, const float* vec2,
    void* out2, float* sAo, float* sBo, int M){
  gfused_impl<KIN, 1, true, false, true, 3>(Ap, Wb1, bias1, nullptr, nullptr,
      nullptr, nullptr, nullptr, nullptr, out1, Wb2, vec2, out2, sAo, sBo, M);
}
__global__ __launch_bounds__(256) void g2_k(
    const void* Ap, const ushort_t* Wb1,
    const ushort_t* WxG, const int* rowptr, const int* cpk,
    const float* sAi, const float* sBi, const float* sCi,
    ushort_t* out1, const ushort_t* Wb2, const float* vec2,
    void* out2, float* sAo, float* sBo, int M){
  gfused_impl<H, 2, false, false, true, 3>(Ap, Wb1, nullptr, WxG, rowptr, cpk,
      sAi, sBi, sCi, out1, Wb2, vec2, out2, sAo, sBo, M);
}
__global__ __launch_bounds__(256) void g3_k(
    const void* Ap, const ushort_t* Wb1,
    const ushort_t* WxG, const int* rowptr, const int* cpk,
    const float* sAi, const float* sBi, const float* sCi,
    const ushort_t* Wb2, const float* vec2, void* out2, int M){
  gfused_impl<H, 2, false, true, false, 1>(Ap, Wb1, nullptr, WxG, rowptr, cpk,
      sAi, sBi, sCi, nullptr, Wb2, vec2, out2, nullptr, nullptr, M);
}

} // namespace

extern "C" void kernel_launch(void* const* d_in, const int* in_sizes, int n_in,
                              void* d_out, int out_size, void* d_ws, size_t ws_size,
                              hipStream_t stream)
{
  const float* x     = (const float*)d_in[0];
  const int*   eidx  = (const int*)d_in[1];
  const int*   et    = (const int*)d_in[2];
  const float* l1W   = (const float*)d_in[3];
  const float* l1b   = (const float*)d_in[4];
  const float* l2W   = (const float*)d_in[5];
  const float* l2b   = (const float*)d_in[6];
  const float* W1    = (const float*)d_in[7];
  const float* Wr1   = (const float*)d_in[8];
  const float* a1    = (const float*)d_in[9];
  const float* Wres1 = (const float*)d_in[10];
  const float* rel1  = (const float*)d_in[11];
  const float* W2    = (const float*)d_in[12];
  const float* Wr2   = (const float*)d_in[13];
  const float* a2    = (const float*)d_in[14];
  const float* Wres2 = (const float*)d_in[15];
  const float* rel2  = (const float*)d_in[16];
  float* outp = (float*)d_out;

  const int* esrc = eidx;        // edge_index[0]
  const int* edst = eidx + E;    // edge_index[1]

  // -------- workspace layout --------
  float* f = (float*)d_ws;
  size_t o = 0;
  float* sA1  = f + o; o += N;
  float* sB1  = f + o; o += N;
  float* sA2  = f + o; o += N;
  float* sB2  = f + o; o += N;
  float* sC1  = f + o; o += 8;
  float* sC2  = f + o; o += 8;
  ushort_t* us = (ushort_t*)(f + o);
  size_t ou = 0;
  ushort_t* b0   = us + ou; ou += (size_t)N * H;    // h0 bf16
  ushort_t* b1   = us + ou; ou += (size_t)N * H;    // h1 bf16
  ushort_t* WxA  = us + ou; ou += (size_t)N * H;    // Wx layer-1 bf16
  ushort_t* WxB  = us + ou; ou += (size_t)N * H;    // Wx layer-2 bf16
  ushort_t* wtsb = us + ou; ou += (size_t)H * KIN + 5 * H * H;
  ushort_t* l1Wb = wtsb;
  ushort_t* W1b  = wtsb + H * KIN;
  ushort_t* R1b  = W1b + H * H;
  ushort_t* W2b  = R1b + H * H;
  ushort_t* R2b  = W2b + H * H;
  ushort_t* l2Wb = R2b + H * H;
  if (ou & 1) ou += 1;
  int* wi = (int*)(us + ou);
  size_t oi = 0;
  int* deg    = wi + oi; oi += N;
  int* rowptr = wi + oi; oi += N + 1;
  int* cursor = wi + oi; oi += N;
  int* bsums  = wi + oi; oi += 256;
  int* boffs  = wi + oi; oi += 256;
  int* cpk    = wi + oi; oi += E;

  const int GB = (N + 63) / 64;

  // -------- cooperative prep + CSR build (single dispatch, 4 grid syncs) --------
  {
    void* args[] = {
      (void*)&l1W, (void*)&W1, (void*)&Wres1, (void*)&W2, (void*)&Wres2,
      (void*)&l2W, (void*)&wtsb,
      (void*)&rel1, (void*)&Wr1, (void*)&a1, (void*)&sC1,
      (void*)&rel2, (void*)&Wr2, (void*)&a2, (void*)&sC2,
      (void*)&esrc, (void*)&edst, (void*)&et,
      (void*)&deg, (void*)&rowptr, (void*)&cursor, (void*)&bsums, (void*)&cpk
    };
    hipLaunchCooperativeKernel((void*)csr_k, dim3(256), dim3(256), args, 0, stream);
  }

  // -------- G1: h0 = leaky(x@l1W^T+b) -> b0;  Wx1 = h0@W1^T -> WxA (+sA1/sB1) --------
  g1_k<<<GB, 256, 0, stream>>>(x, l1Wb, l1b, b0, W1b, a1, WxA, sA1, sB1, N);

  // -------- G2: agg1 (in-block); h1 = elu(agg1 + b0@R1^T) -> b1; Wx2 -> WxB --------
  g2_k<<<GB, 256, 0, stream>>>(b0, R1b, WxA, rowptr, cpk, sA1, sB1, sC1,
                               b1, W2b, a2, WxB, sA2, sB2, N);

  // -------- G3: agg2 (in-block); h2 = normalize(elu(agg2 + b1@R2^T)); out --------
  g3_k<<<GB, 256, 0, stream>>>(b1, R2b, WxB, rowptr, cpk, sA2, sB2, sC2,
                               l2Wb, l2b, outp, N);
}

// Round 9
// 517.023 us; speedup vs baseline: 1.2059x; 1.2059x over previous
//
#include <hip/hip_runtime.h>

namespace {

typedef unsigned short ushort_t;
typedef unsigned int uint_t;
typedef __attribute__((ext_vector_type(8))) short bf16x8;
typedef __attribute__((ext_vector_type(4))) float f32x4;

constexpr int N   = 50000;
constexpr int E   = 600000;
constexpr int NR  = 5;
constexpr int KIN = 768;
constexpr int H   = 128;
constexpr int RD  = 200;

__device__ inline ushort_t f2b(float f){           // fp32 -> bf16 bits, RNE
  uint_t u = __builtin_bit_cast(uint_t, f);
  uint_t r = (u + 0x7FFFu + ((u >> 16) & 1u)) >> 16;
  return (ushort_t)r;
}
__device__ inline float b2f_lo(uint_t u){ return __builtin_bit_cast(float, u << 16); }
__device__ inline float b2f_hi(uint_t u){ return __builtin_bit_cast(float, u & 0xFFFF0000u); }
__device__ inline float b2f_us(ushort_t h){ return __builtin_bit_cast(float, ((uint_t)h) << 16); }
__device__ inline uint_t cvtpk(float lo, float hi){ // 2x fp32 -> packed bf16 (RNE), 1 instr
  uint_t r;
  asm("v_cvt_pk_bf16_f32 %0, %1, %2" : "=v"(r) : "v"(lo), "v"(hi));
  return r;
}

// ---- prep: weight cvt (blocks 0..703) + relsc (704..705) + degcount (706..) ----
__global__ void prep_k(const float* __restrict__ l1W, const float* __restrict__ W1,
                       const float* __restrict__ R1, const float* __restrict__ W2,
                       const float* __restrict__ R2, const float* __restrict__ l2W,
                       ushort_t* __restrict__ wts, int* __restrict__ deg,
                       const int* __restrict__ edst,
                       const float* __restrict__ rel1, const float* __restrict__ Wr1,
                       const float* __restrict__ a1, float* __restrict__ sC1,
                       const float* __restrict__ rel2, const float* __restrict__ Wr2,
                       const float* __restrict__ a2, float* __restrict__ sC2){
  constexpr int S0 = H * KIN;        // 98304
  constexpr int S1 = H * H;          // 16384
  int b = blockIdx.x, tid = threadIdx.x;
  if (b < 704){                      // weight convert: 704*256 == S0 + 5*S1 exactly
    int i = b * 256 + tid;
    float v;
    if (i < S0) v = l1W[i];
    else {
      int j = i - S0, seg = j >> 14, off = j & (S1 - 1);
      const float* srcs[5] = {W1, R1, W2, R2, l2W};
      v = srcs[seg][off];
    }
    wts[i] = f2b(v);
  } else if (b < 706){               // relation scalars, one block per layer
    int L = b - 704;
    const float* rel = L ? rel2 : rel1;
    const float* Wr  = L ? Wr2  : Wr1;
    const float* a   = L ? a2   : a1;
    float*       sC  = L ? sC2  : sC1;
    __shared__ float red[256];
    int n = tid >> 1, half = tid & 1;
    float aC = a[256 + n];
    for (int r = 0; r < NR; ++r){
      float p = 0.f;
      for (int k = half * 100; k < half * 100 + 100; ++k)
        p += rel[r * RD + k] * Wr[n * RD + k];
      red[tid] = p * aC;
      __syncthreads();
      for (int s = 128; s > 0; s >>= 1){
        if (tid < s) red[tid] += red[tid + s];
        __syncthreads();
      }
      if (tid == 0) sC[r] = red[0];
      __syncthreads();
    }
  } else {                           // degree count
    int e = (b - 706) * 256 + tid;
    if (e < E) atomicAdd(&deg[edst[e]], 1);
  }
}

// ---- merged scan: per-chunk scan + device-wide spin barrier + prefix add ----
// 196 blocks (all trivially co-resident: 2KB LDS, low VGPR). Arrival protocol:
// tid255 stores bsums, __threadfence(), atomicAdd(flag). All blocks spin until
// flag==nb, fence, then every block redundantly scans bsums for its prefix.
__global__ void scanall_k(const int* __restrict__ deg, int* __restrict__ rowptr,
                          int* __restrict__ cursor, int* __restrict__ bsums,
                          int* __restrict__ flag, int n, int total, int nb){
  __shared__ int s[256];
  const int tid = threadIdx.x, bid = blockIdx.x;
  const int i = bid * 256 + tid;
  int v = (i < n) ? deg[i] : 0;
  s[tid] = v; __syncthreads();
  for (int off = 1; off < 256; off <<= 1){
    int t = (tid >= off) ? s[tid - off] : 0;
    __syncthreads();
    s[tid] += t;
    __syncthreads();
  }
  int chunkexcl = s[tid] - v;
  if (tid == 255){
    bsums[bid] = s[255];
    __threadfence();
    atomicAdd(flag, 1);
  }
  if (tid == 0){
    while (atomicAdd(flag, 0) < nb){ __builtin_amdgcn_s_sleep(8); }
  }
  __syncthreads();
  __threadfence();
  // phase B: every block scans bsums redundantly
  int bv = (tid < nb) ? bsums[tid] : 0;
  s[tid] = bv; __syncthreads();
  for (int off = 1; off < 256; off <<= 1){
    int t = (tid >= off) ? s[tid - off] : 0;
    __syncthreads();
    s[tid] += t;
    __syncthreads();
  }
  int add = s[bid] - bsums[bid];           // exclusive prefix for this block
  if (i < n){
    int val = chunkexcl + add;
    rowptr[i] = val; cursor[i] = val;
  }
  if (i == 0) rowptr[n] = total;
}

// fill CSR adjacency with (type<<16)|src packed (src < 65536, type < 8)
__global__ void fill_k(const int* __restrict__ src, const int* __restrict__ dst,
                       const int* __restrict__ et, int* __restrict__ cursor,
                       int* __restrict__ cpk){
  int e = blockIdx.x * 256 + threadIdx.x;
  if (e < E){
    int d = dst[e];
    int p = atomicAdd(&cursor[d], 1);
    cpk[p] = src[e] | (et[e] << 16);
  }
}

// --------- fused [agg +] double-GEMM, shared impl; BKT-parameterized k-step ---------
// 64x128 tile, 4 waves, 2-phase reg prefetch; GEMM2 B staged in dead U region.
// M1: 1 = +bias1, leaky(0.01)    2 = in-block agg (16-lane grp/node) + elu(acc+agg)
// NORM: row L2-normalize; STORE1: bf16 stage-1 out; M2: 1 = fp32 out, 3 = bf16 + sA/sB
template<int K1, int BKT, int M1, bool AFP32, bool NORM, bool STORE1, int M2>
__device__ __forceinline__ void gfused_impl(
    const void* __restrict__ Ap, const ushort_t* __restrict__ Wb1,
    const float* __restrict__ bias1,
    const ushort_t* __restrict__ WxG, const int* __restrict__ rowptr,
    const int* __restrict__ cpk, const float* __restrict__ sAi,
    const float* __restrict__ sBi, const float* __restrict__ sCi,
    ushort_t* __restrict__ out1,
    const ushort_t* __restrict__ Wb2, const float* __restrict__ vec2,
    void* __restrict__ out2, float* __restrict__ sAo, float* __restrict__ sBo, int M)
{
  constexpr int BK = BKT;              // k-step (96 for G1, 64 for G2/G3)
  constexpr int NT = K1 / BK;          // 8 (G1) or 2 (G2/G3)
  constexpr int SP = BK + 8;           // staging row stride (bf16 elems)
  constexpr int CP = 136;              // Cs/B2s stride; 272 B rows
  constexpr int UE = (192 * SP > 128 * CP) ? 192 * SP : 128 * CP;
  __shared__ __align__(16) ushort_t U[UE];         // As+Bs | B2s overlay
  __shared__ __align__(16) ushort_t Cs[64 * CP];   // 17408 B
  ushort_t* const As  = U;                          // 64 x SP
  ushort_t* const Bs  = U + 64 * SP;                // 128 x SP
  ushort_t* const B2s = U;                          // 128 x CP after GEMM1
  const int tid  = threadIdx.x;
  const int wave = tid >> 6, lane = tid & 63;
  const int l15  = lane & 15, quad = lane >> 4;
  const int row0 = blockIdx.x * 64;

  // ---- M1==2: in-block aggregation for this block's 64 nodes -> Cs ----
  if (M1 == 2){
    const int grp = tid >> 4;       // 16 groups of 16 lanes
    const int l   = tid & 15;
    const int gb  = tid & 48;       // group base lane within wave
    #pragma unroll 1
    for (int nb = 0; nb < 4; ++nb){
      int lrow = nb * 16 + grp;
      int node = row0 + lrow;
      uint4 o = make_uint4(0, 0, 0, 0);
      if (node < M){
        int p0 = rowptr[node], p1 = rowptr[node + 1];
        int dg = p1 - p0;
        float sa = sAi[node];
        float m = -1e30f, ssum = 0.f;
        float a[8];
        #pragma unroll
        for (int j = 0; j < 8; ++j) a[j] = 0.f;
        for (int c0 = 0; c0 < dg; c0 += 16){
          int cnt = dg - c0; if (cnt > 16) cnt = 16;
          bool ok = l < cnt;
          int pk = cpk[p0 + c0 + (ok ? l : 0)];
          float s = sa + sBi[pk & 0xFFFF] + sCi[pk >> 16];
          s = s > 0.f ? s : 0.2f * s;                    // leaky_relu(., 0.2)
          float sv = ok ? s : -1e30f;
          #pragma unroll
          for (int off = 8; off > 0; off >>= 1) sv = fmaxf(sv, __shfl_xor(sv, off, 16));
          float mn = fmaxf(m, sv);
          float corr = __expf(m - mn);
          ssum *= corr;
          #pragma unroll
          for (int j = 0; j < 8; ++j) a[j] *= corr;
          float ev = ok ? __expf(s - mn) : 0.f;
          float es = ev;
          #pragma unroll
          for (int off = 8; off > 0; off >>= 1) es += __shfl_xor(es, off, 16);
          ssum += es;
          m = mn;
          int png = ok ? pk : 0;
          for (int e = 0; e < cnt; e += 4){              // tails neutralized by ev=0
            int b0l = gb + e;
            int pe0 = __shfl(png, b0l,     64), pe1 = __shfl(png, b0l + 1, 64);
            int pe2 = __shfl(png, b0l + 2, 64), pe3 = __shfl(png, b0l + 3, 64);
            float e0 = __shfl(ev, b0l,     64), e1 = __shfl(ev, b0l + 1, 64);
            float e2 = __shfl(ev, b0l + 2, 64), e3 = __shfl(ev, b0l + 3, 64);
            uint4 u0 = *reinterpret_cast<const uint4*>(WxG + (size_t)(pe0 & 0xFFFF) * 128 + l * 8);
            uint4 u1 = *reinterpret_cast<const uint4*>(WxG + (size_t)(pe1 & 0xFFFF) * 128 + l * 8);
            uint4 u2 = *reinterpret_cast<const uint4*>(WxG + (size_t)(pe2 & 0xFFFF) * 128 + l * 8);
            uint4 u3 = *reinterpret_cast<const uint4*>(WxG + (size_t)(pe3 & 0xFFFF) * 128 + l * 8);
            a[0] += e0 * b2f_lo(u0.x); a[1] += e0 * b2f_hi(u0.x);
            a[2] += e0 * b2f_lo(u0.y); a[3] += e0 * b2f_hi(u0.y);
            a[4] += e0 * b2f_lo(u0.z); a[5] += e0 * b2f_hi(u0.z);
            a[6] += e0 * b2f_lo(u0.w); a[7] += e0 * b2f_hi(u0.w);
            a[0] += e1 * b2f_lo(u1.x); a[1] += e1 * b2f_hi(u1.x);
            a[2] += e1 * b2f_lo(u1.y); a[3] += e1 * b2f_hi(u1.y);
            a[4] += e1 * b2f_lo(u1.z); a[5] += e1 * b2f_hi(u1.z);
            a[6] += e1 * b2f_lo(u1.w); a[7] += e1 * b2f_hi(u1.w);
            a[0] += e2 * b2f_lo(u2.x); a[1] += e2 * b2f_hi(u2.x);
            a[2] += e2 * b2f_lo(u2.y); a[3] += e2 * b2f_hi(u2.y);
            a[4] += e2 * b2f_lo(u2.z); a[5] += e2 * b2f_hi(u2.z);
            a[6] += e2 * b2f_lo(u2.w); a[7] += e2 * b2f_hi(u2.w);
            a[0] += e3 * b2f_lo(u3.x); a[1] += e3 * b2f_hi(u3.x);
            a[2] += e3 * b2f_lo(u3.y); a[3] += e3 * b2f_hi(u3.y);
            a[4] += e3 * b2f_lo(u3.z); a[5] += e3 * b2f_hi(u3.z);
            a[6] += e3 * b2f_lo(u3.w); a[7] += e3 * b2f_hi(u3.w);
          }
        }
        float inv = (dg > 0) ? 1.f / ssum : 0.f;        // degree-0 -> zero row
        o.x = cvtpk(a[0] * inv, a[1] * inv);
        o.y = cvtpk(a[2] * inv, a[3] * inv);
        o.z = cvtpk(a[4] * inv, a[5] * inv);
        o.w = cvtpk(a[6] * inv, a[7] * inv);
      }
      *reinterpret_cast<uint4*>(&Cs[lrow * CP + l * 8]) = o;   // cols l*8..l*8+7
    }
  }

  f32x4 acc[8];
  #pragma unroll
  for (int t = 0; t < 8; ++t) acc[t] = (f32x4){0.f, 0.f, 0.f, 0.f};

  // ================= GEMM 1: A[M x K1] @ W1^T, BK-step, prefetched =================
  constexpr int AF4 = BK / 16;   // float4/thread (fp32 A prefetch)
  constexpr int AU4 = BK / 32;   // uint4/thread (bf16 A)
  constexpr int BU4 = BK / 16;   // uint4/thread (B)
  const int ar = tid >> 2, aq = tid & 3;           // A: row 0..63, quarter-seg
  const int agrow = row0 + ar;
  const bool aok = agrow < M;
  const int awoff = ar * SP + aq * (BK / 4);
  const int bn = tid >> 1, bs = (tid & 1) * (BK / 2);   // B: n-row, half-seg
  const ushort_t* bsrc = Wb1 + (size_t)bn * K1 + bs;

  float4 pfa[AF4] = {};
  uint4  pua[AU4] = {};
  uint4  pb[BU4];

#define ISSUE_A(kk) do{ if (aok){                                               \
    if constexpr (AFP32){                                                       \
      const float* ap_ = (const float*)Ap + (size_t)agrow * K1 + (kk) + aq * (BK / 4); \
      _Pragma("unroll") for (int j_ = 0; j_ < AF4; ++j_)                        \
        pfa[j_] = *reinterpret_cast<const float4*>(ap_ + j_ * 4);               \
    } else {                                                                    \
      const ushort_t* apb_ = (const ushort_t*)Ap + (size_t)agrow * K1 + (kk) + aq * (BK / 4); \
      _Pragma("unroll") for (int j_ = 0; j_ < AU4; ++j_)                        \
        pua[j_] = *reinterpret_cast<const uint4*>(apb_ + j_ * 8);               \
    } } }while(0)

#define ISSUE_B(kk) do{                                                         \
    _Pragma("unroll") for (int j_ = 0; j_ < BU4; ++j_)                          \
      pb[j_] = *reinterpret_cast<const uint4*>(bsrc + (kk) + j_ * 8);           \
  }while(0)

#define WRITE_AB() do{                                                          \
    if constexpr (AFP32){                                                       \
      _Pragma("unroll") for (int j_ = 0; j_ < AU4; ++j_){                       \
        uint4 av_;                                                              \
        av_.x = cvtpk(pfa[2*j_].x, pfa[2*j_].y);                                \
        av_.y = cvtpk(pfa[2*j_].z, pfa[2*j_].w);                                \
        av_.z = cvtpk(pfa[2*j_+1].x, pfa[2*j_+1].y);                            \
        av_.w = cvtpk(pfa[2*j_+1].z, pfa[2*j_+1].w);                            \
        *reinterpret_cast<uint4*>(&As[awoff + j_ * 8]) = av_;                   \
      }                                                                         \
    } else {                                                                    \
      _Pragma("unroll") for (int j_ = 0; j_ < AU4; ++j_)                        \
        *reinterpret_cast<uint4*>(&As[awoff + j_ * 8]) = pua[j_];               \
    }                                                                           \
    _Pragma("unroll") for (int j_ = 0; j_ < BU4; ++j_)                          \
      *reinterpret_cast<uint4*>(&Bs[bn * SP + bs + j_ * 8]) = pb[j_];           \
  }while(0)

  ISSUE_A(0); ISSUE_B(0);
  for (int t = 0; t < NT; ++t){
    WRITE_AB();
    __syncthreads();
    if (t + 1 < NT){ ISSUE_A((t + 1) * BK); ISSUE_B((t + 1) * BK); }
    #pragma unroll
    for (int kk = 0; kk < BK / 32; ++kk){
      bf16x8 af = *reinterpret_cast<const bf16x8*>(&As[(wave * 16 + l15) * SP + kk * 32 + quad * 8]);
      #pragma unroll
      for (int tt = 0; tt < 8; ++tt){
        bf16x8 bfr = *reinterpret_cast<const bf16x8*>(&Bs[(tt * 16 + l15) * SP + kk * 32 + quad * 8]);
        acc[tt] = __builtin_amdgcn_mfma_f32_16x16x32_bf16(af, bfr, acc[tt], 0, 0, 0);
      }
    }
    __syncthreads();
  }
#undef ISSUE_A
#undef ISSUE_B
#undef WRITE_AB

  // ---- issue GEMM2 B loads first (latency hides under epilogue-1 VALU) ----
  uint4 wreg[8];
  #pragma unroll
  for (int i = 0; i < 8; ++i){
    int idx = tid + 256 * i;                 // 2048 chunks of 8 bf16
    int rr = idx >> 4, c8 = idx & 15;
    wreg[i] = *reinterpret_cast<const uint4*>(Wb2 + (size_t)rr * 128 + c8 * 8);
  }

  // ---- epilogue 1: C/D map col=t*16+l15, local row lr=wave*16+quad*4+r ----
  float vv[8][4];
  #pragma unroll
  for (int t = 0; t < 8; ++t){
    #pragma unroll
    for (int r = 0; r < 4; ++r){
      int lr  = wave * 16 + quad * 4 + r;
      int col = t * 16 + l15;
      float v = acc[t][r];
      if (M1 == 1){
        v += bias1[col];
        v = v > 0.f ? v : 0.01f * v;
      } else { // M1 == 2
        v += b2f_us(Cs[lr * CP + col]);      // same cell this thread rewrites below
        v = v > 0.f ? v : __expf(v) - 1.f;
      }
      vv[t][r] = v;
    }
  }
  // write staged B2 (As/Bs region dead after last k-loop barrier)
  #pragma unroll
  for (int i = 0; i < 8; ++i){
    int idx = tid + 256 * i;
    int rr = idx >> 4, c8 = idx & 15;
    *reinterpret_cast<uint4*>(&B2s[rr * CP + c8 * 8]) = wreg[i];
  }
  if (NORM){
    #pragma unroll
    for (int r = 0; r < 4; ++r){
      float ss = 0.f;
      #pragma unroll
      for (int t = 0; t < 8; ++t) ss += vv[t][r] * vv[t][r];
      #pragma unroll
      for (int off = 1; off < 16; off <<= 1) ss += __shfl_xor(ss, off, 64);
      float sc = 1.f / fmaxf(sqrtf(ss), 1e-12f);
      #pragma unroll
      for (int t = 0; t < 8; ++t) vv[t][r] *= sc;
    }
  }
  #pragma unroll
  for (int t = 0; t < 8; t += 2){
    #pragma unroll
    for (int r = 0; r < 4; ++r){
      int lr  = wave * 16 + quad * 4 + r;
      int c0  = t * 16 + l15, c1 = c0 + 16;
      uint_t pr = cvtpk(vv[t][r], vv[t + 1][r]);
      Cs[lr * CP + c0] = (ushort_t)pr;
      Cs[lr * CP + c1] = (ushort_t)(pr >> 16);
      if (STORE1){
        int grow = row0 + lr;
        if (grow < M){
          out1[(size_t)grow * 128 + c0] = (ushort_t)pr;
          out1[(size_t)grow * 128 + c1] = (ushort_t)(pr >> 16);
        }
      }
    }
  }
  __syncthreads();

  // ================= GEMM 2: Cs[64 x 128] @ W2^T, fully staged =================
  #pragma unroll
  for (int t = 0; t < 8; ++t) acc[t] = (f32x4){0.f, 0.f, 0.f, 0.f};
  #pragma unroll
  for (int kk = 0; kk < 4; ++kk){
    bf16x8 af2 = *reinterpret_cast<const bf16x8*>(&Cs[(wave * 16 + l15) * CP + kk * 32 + quad * 8]);
    #pragma unroll
    for (int t = 0; t < 8; ++t){
      bf16x8 bfr = *reinterpret_cast<const bf16x8*>(&B2s[(t * 16 + l15) * CP + kk * 32 + quad * 8]);
      acc[t] = __builtin_amdgcn_mfma_f32_16x16x32_bf16(af2, bfr, acc[t], 0, 0, 0);
    }
  }

  // ---- epilogue 2 ----
  if (M2 == 1){
    #pragma unroll
    for (int t = 0; t < 8; ++t){
      #pragma unroll
      for (int r = 0; r < 4; ++r){
        int grow = row0 + wave * 16 + quad * 4 + r;
        if (grow >= M) continue;
        int col = t * 16 + l15;
        float v = acc[t][r] + vec2[col];
        v = v > 0.f ? v : 0.01f * v;
        ((float*)out2)[(size_t)grow * 128 + col] = v;
      }
    }
  } else { // M2 == 3: bf16 out + per-row sA/sB
    #pragma unroll
    for (int t = 0; t < 8; t += 2){
      #pragma unroll
      for (int r = 0; r < 4; ++r){
        int grow = row0 + wave * 16 + quad * 4 + r;
        if (grow >= M) continue;
        int c0 = t * 16 + l15;
        uint_t pr = cvtpk(acc[t][r], acc[t + 1][r]);
        ((ushort_t*)out2)[(size_t)grow * 128 + c0]      = (ushort_t)pr;
        ((ushort_t*)out2)[(size_t)grow * 128 + c0 + 16] = (ushort_t)(pr >> 16);
      }
    }
    #pragma unroll
    for (int r = 0; r < 4; ++r){
      float pa = 0.f, pb = 0.f;
      #pragma unroll
      for (int t = 0; t < 8; ++t){
        int col = t * 16 + l15;
        pa += acc[t][r] * vec2[col];
        pb += acc[t][r] * vec2[128 + col];
      }
      #pragma unroll
      for (int off = 1; off < 16; off <<= 1){
        pa += __shfl_xor(pa, off, 64);
        pb += __shfl_xor(pb, off, 64);
      }
      int grow = row0 + wave * 16 + quad * 4 + r;
      if (l15 == r && grow < M){ sAo[grow] = pa; sBo[grow] = pb; }
    }
  }
}

// ---- distinctly-named kernels per stage (rocprof visibility) ----
__global__ __launch_bounds__(256) void g1_k(
    const void* Ap, const ushort_t* Wb1, const float* bias1,
    ushort_t* out1, const ushort_t* Wb2, const float* vec2,
    void* out2, float* sAo, float* sBo, int M){
  gfused_impl<KIN, 96, 1, true, false, true, 3>(Ap, Wb1, bias1, nullptr, nullptr,
      nullptr, nullptr, nullptr, nullptr, out1, Wb2, vec2, out2, sAo, sBo, M);
}
__global__ __launch_bounds__(256) void g2_k(
    const void* Ap, const ushort_t* Wb1,
    const ushort_t* WxG, const int* rowptr, const int* cpk,
    const float* sAi, const float* sBi, const float* sCi,
    ushort_t* out1, const ushort_t* Wb2, const float* vec2,
    void* out2, float* sAo, float* sBo, int M){
  gfused_impl<H, 64, 2, false, false, true, 3>(Ap, Wb1, nullptr, WxG, rowptr, cpk,
      sAi, sBi, sCi, out1, Wb2, vec2, out2, sAo, sBo, M);
}
__global__ __launch_bounds__(256) void g3_k(
    const void* Ap, const ushort_t* Wb1,
    const ushort_t* WxG, const int* rowptr, const int* cpk,
    const float* sAi, const float* sBi, const float* sCi,
    const ushort_t* Wb2, const float* vec2, void* out2, int M){
  gfused_impl<H, 64, 2, false, true, false, 1>(Ap, Wb1, nullptr, WxG, rowptr, cpk,
      sAi, sBi, sCi, nullptr, Wb2, vec2, out2, nullptr, nullptr, M);
}

} // namespace

extern "C" void kernel_launch(void* const* d_in, const int* in_sizes, int n_in,
                              void* d_out, int out_size, void* d_ws, size_t ws_size,
                              hipStream_t stream)
{
  const float* x     = (const float*)d_in[0];
  const int*   eidx  = (const int*)d_in[1];
  const int*   et    = (const int*)d_in[2];
  const float* l1W   = (const float*)d_in[3];
  const float* l1b   = (const float*)d_in[4];
  const float* l2W   = (const float*)d_in[5];
  const float* l2b   = (const float*)d_in[6];
  const float* W1    = (const float*)d_in[7];
  const float* Wr1   = (const float*)d_in[8];
  const float* a1    = (const float*)d_in[9];
  const float* Wres1 = (const float*)d_in[10];
  const float* rel1  = (const float*)d_in[11];
  const float* W2    = (const float*)d_in[12];
  const float* Wr2   = (const float*)d_in[13];
  const float* a2    = (const float*)d_in[14];
  const float* Wres2 = (const float*)d_in[15];
  const float* rel2  = (const float*)d_in[16];
  float* outp = (float*)d_out;

  const int* esrc = eidx;        // edge_index[0]
  const int* edst = eidx + E;    // edge_index[1]

  // -------- workspace layout --------
  float* f = (float*)d_ws;
  size_t o = 0;
  float* sA1  = f + o; o += N;
  float* sB1  = f + o; o += N;
  float* sA2  = f + o; o += N;
  float* sB2  = f + o; o += N;
  float* sC1  = f + o; o += 8;
  float* sC2  = f + o; o += 8;
  ushort_t* us = (ushort_t*)(f + o);
  size_t ou = 0;
  ushort_t* b0   = us + ou; ou += (size_t)N * H;    // h0 bf16
  ushort_t* b1   = us + ou; ou += (size_t)N * H;    // h1 bf16
  ushort_t* WxA  = us + ou; ou += (size_t)N * H;    // Wx layer-1 bf16
  ushort_t* WxB  = us + ou; ou += (size_t)N * H;    // Wx layer-2 bf16
  ushort_t* wtsb = us + ou; ou += (size_t)H * KIN + 5 * H * H;
  ushort_t* l1Wb = wtsb;
  ushort_t* W1b  = wtsb + H * KIN;
  ushort_t* R1b  = W1b + H * H;
  ushort_t* W2b  = R1b + H * H;
  ushort_t* R2b  = W2b + H * H;
  ushort_t* l2Wb = R2b + H * H;
  if (ou & 1) ou += 1;
  int* wi = (int*)(us + ou);
  size_t oi = 0;
  int* deg     = wi + oi; oi += N;
  int* scanflg = wi + oi; oi += 1;      // contiguous after deg: memset zeroes both
  int* rowptr  = wi + oi; oi += N + 1;
  int* cursor  = wi + oi; oi += N;
  int* bsums   = wi + oi; oi += 256;
  int* cpk     = wi + oi; oi += E;

  const int EB    = (E + 255) / 256;
  const int NB256 = (N + 255) / 256;
  const int GB    = (N + 63) / 64;

  // -------- prep (deg+flag zero via memset; weight cvt + relsc + degcount fused) --------
  hipMemsetAsync(deg, 0, (size_t)(N + 1) * sizeof(int), stream);
  prep_k<<<706 + EB, 256, 0, stream>>>(l1W, W1, Wres1, W2, Wres2, l2W, wtsb, deg,
                                       edst, rel1, Wr1, a1, sC1, rel2, Wr2, a2, sC2);
  scanall_k<<<NB256, 256, 0, stream>>>(deg, rowptr, cursor, bsums, scanflg, N, E, NB256);
  fill_k<<<EB, 256, 0, stream>>>(esrc, edst, et, cursor, cpk);

  // -------- G1: h0 = leaky(x@l1W^T+b) -> b0;  Wx1 = h0@W1^T -> WxA (+sA1/sB1) --------
  g1_k<<<GB, 256, 0, stream>>>(x, l1Wb, l1b, b0, W1b, a1, WxA, sA1, sB1, N);

  // -------- G2: agg1 (in-block); h1 = elu(agg1 + b0@R1^T) -> b1; Wx2 -> WxB --------
  g2_k<<<GB, 256, 0, stream>>>(b0, R1b, WxA, rowptr, cpk, sA1, sB1, sC1,
                               b1, W2b, a2, WxB, sA2, sB2, N);

  // -------- G3: agg2 (in-block); h2 = normalize(elu(agg2 + b1@R2^T)); out --------
  g3_k<<<GB, 256, 0, stream>>>(b1, R2b, WxB, rowptr, cpk, sA2, sB2, sC2,
                               l2Wb, l2b, outp, N);
}